// Round 11
// baseline (74445.435 us; speedup 1.0000x reference)
//
#include <hip/hip_runtime.h>
#include <hip/hip_bf16.h>
#include <math.h>

// ============================================================================
// RNNDecoder v13: v12 (2 blocks/row, relaxed exchange) + L2-residency and
// critical-path fixes:
//  1. XCD-role partition: A-blocks on XCDs 0-3, B-blocks on 4-7 (blk%8->XCD
//     heuristic; correctness-independent). B-XCDs' weight set (~2 MB) becomes
//     fully L2-resident; A-XCDs' weights (~1.6 MB) resident beside ulat.
//  2. Non-temporal ulat loads (scores + cu) stop the 4 MB/XCD ulat stream
//     from evicting weights.
//  3. B's tok poll moved from end-of-step to after its next GRU dots: B's
//     GRU overlaps A's logits + tok publication (RTT hidden).
// All compute chains byte-identical to v12 (= verbatim v4-v9 chains; same
// argmax trajectory).
// ============================================================================

typedef unsigned short u16;
typedef unsigned int u32;
typedef float f4 __attribute__((ext_vector_type(4)));
typedef u32 u4 __attribute__((ext_vector_type(4)));

#define NB 256
#define NT 512
#define Ln 500
#define Hn 512
#define LDn 256
#define UDn 128
#define Vn 33
#define Tn 500
#define SENT_V 0x9E3779B1u

// ---- workspace u32 offsets (128 pairs) ----
#define W_INITC 0u
#define W_SENT  1u
#define W_FLG   64u        // [128 pair][8 kind][8 pad]; 0=hA 1=hB 2=cu 3=ccB 4=tok
#define W_HX    8256u      // f32 [128][512] h exchange
#define W_CUX   73792u     // f32 [128][128]
#define W_CCX   90176u     // f32 [128][512] (B writes [128,512))
#define W_TOKX  155712u    // int [128][8]
#define W_GEM   156736u    // f32 [33][1536]
#define W_M2    207424u    // f32 [512][128]
#define W_CB    272960u    // f32 [512]
#define W_MWT   273472u    // f32 [128][512] memW^T
#define W_END   339008u    // ~1.36 MB

__device__ __forceinline__ float b2f(u16 v) {
  u32 x = ((u32)v) << 16; float f; __builtin_memcpy(&f, &x, 4); return f;
}
__device__ __forceinline__ float bitsf(u32 x) {
  float f; __builtin_memcpy(&f, &x, 4); return f;
}
#define LO16(d) bitsf((u32)(d) << 16)
#define HI16(d) bitsf((u32)(d) & 0xffff0000u)
__device__ __forceinline__ u16 f2b(float f) {  // RNE
  u32 x; __builtin_memcpy(&x, &f, 4);
  x += 0x7fffu + ((x >> 16) & 1u);
  return (u16)(x >> 16);
}
__device__ __forceinline__ float ldv(const void* p, size_t i, int mode) {
  return mode ? b2f(((const u16*)p)[i]) : ((const float*)p)[i];
}
__device__ __forceinline__ u32 aload(u32* p) {
  return __hip_atomic_load(p, __ATOMIC_ACQUIRE, __HIP_MEMORY_SCOPE_AGENT);
}
__device__ __forceinline__ void waitGe(u32* p, u32 tgt) {
  while (aload(p) < tgt) __builtin_amdgcn_s_sleep(4);
}
__device__ __forceinline__ void astore(u32* p, u32 v) {
  __hip_atomic_store(p, v, __ATOMIC_RELEASE, __HIP_MEMORY_SCOPE_AGENT);
}
// ---- fully-relaxed exchange primitives (no L2 cache maintenance) ----
__device__ __forceinline__ void rarrive(u32* p) {  // relaxed RMW @ coherence pt
  __hip_atomic_fetch_add(p, 1u, __ATOMIC_RELAXED, __HIP_MEMORY_SCOPE_AGENT);
}
__device__ __forceinline__ void pace_zero(u32* p) {
  __hip_atomic_store(p, 0u, __ATOMIC_RELAXED, __HIP_MEMORY_SCOPE_AGENT);
}
__device__ __forceinline__ void rpoll(u32* p, u32 tgt) {  // relaxed-only poll
  while (__hip_atomic_load(p, __ATOMIC_RELAXED, __HIP_MEMORY_SCOPE_AGENT) < tgt)
    __builtin_amdgcn_s_sleep(2);
}
__device__ __forceinline__ void rstoref(float* p, float v) {
  u32 x; __builtin_memcpy(&x, &v, 4);
  __hip_atomic_store((u32*)p, x, __ATOMIC_RELAXED, __HIP_MEMORY_SCOPE_AGENT);
}
__device__ __forceinline__ float rloadf(const float* p) {
  u32 x = __hip_atomic_load((const u32*)p, __ATOMIC_RELAXED, __HIP_MEMORY_SCOPE_AGENT);
  float f; __builtin_memcpy(&f, &x, 4); return f;
}
__device__ __forceinline__ void rstorei(int* p, int v) {
  __hip_atomic_store((u32*)p, (u32)v, __ATOMIC_RELAXED, __HIP_MEMORY_SCOPE_AGENT);
}
__device__ __forceinline__ int rloadi(const int* p) {
  return (int)__hip_atomic_load((const u32*)p, __ATOMIC_RELAXED, __HIP_MEMORY_SCOPE_AGENT);
}
__device__ __forceinline__ void stage16(const void* g, void* l) {
  __builtin_amdgcn_global_load_lds(
      (const __attribute__((address_space(1))) u32*)g,
      (__attribute__((address_space(3))) u32*)l, 16, 0, 0);
}

extern "C" __global__ void __launch_bounds__(512, 2)
rnn_v13(const void* latent, const void* ulat, const void* embd,
        const void* hidW, const void* hidb, const void* memW, const void* memb,
        const void* Wih, const void* Whh, const void* bih, const void* bhh,
        const void* catW, const void* catb, const void* outW, const void* outb,
        void* out, u32* ws) {
  __shared__ __align__(16) char  stage[131072];
  __shared__ __align__(16) char  arena[12288];
  __shared__ __align__(16) float bhh_l[1536];
  __shared__ __align__(16) float h_l[Hn];
  __shared__ float misc_l[2];
  __shared__ int   s_tok;
  __shared__ u32   s_det;

  const int tid = threadIdx.x, blk = blockIdx.x;
  const int wv = tid >> 6, lane = tid & 63;
  // XCD-role partition: blk%8 -> XCD (heuristic). A on XCDs 0-3, B on 4-7.
  const int role = (blk >> 2) & 1;           // blk&7 in {0..3}=A, {4..7}=B
  const int pr = (blk >> 3) * 4 + (blk & 3); // pair row 0..127 (each role once)
  const int gtid = blk * NT + tid;

  if (tid == 0) s_det = 0u;
  __syncthreads();
  if (tid < 256) {
    u32 v = ((const u32*)embd)[256 + tid];
    if (v) atomicOr(&s_det, 1u);
  }
  __syncthreads();
  const int mode = (s_det == 0u) ? 1 : 0;

  float* GEM = (float*)(ws + W_GEM);
  float* M2  = (float*)(ws + W_M2);
  float* cbF = (float*)(ws + W_CB);
  float* mWT = (float*)(ws + W_MWT);
  float* HX  = (float*)(ws + W_HX) + (size_t)pr * 512;
  float* CUX = (float*)(ws + W_CUX) + (size_t)pr * 128;
  float* CCX = (float*)(ws + W_CCX) + (size_t)pr * 512;
  int*   TKX = (int*)(ws + W_TOKX) + (size_t)pr * 8;
  u32*   FLG = ws + W_FLG + (u32)pr * 64u;   // + kind*8

  float* ghq   = (float*)arena;            // GRU: [768] local rows
  float* pa    = (float*)arena;            // B cc: [384][2] partials (post-gates)
  float* ps    = (float*)arena;            // A attn
  float* ss    = (float*)(arena + 512);
  float* es    = (float*)(arena + 2560);
  float* Bpart = (float*)(arena + 4608);
  float* cuv   = (float*)(arena + 8704);
  float* ccs   = (float*)(arena + 4608);   // A: [512] cc gather
  float* lgs   = (float*)(arena + 6656);

  // ======================= per-block init ===================================
  for (int i = tid; i < 1536; i += NT) bhh_l[i] = ldv(bhh, i, mode);
  {  // full h0 (verbatim chain), computed redundantly by both pair members
    int k = tid;
    float a = ldv(hidb, k, mode);
    for (int q = 0; q < LDn; q++)
      a += ldv(latent, (size_t)pr * LDn + q, mode) * ldv(hidW, (size_t)k * LDn + q, mode);
    h_l[k] = a;
  }
  if (tid == 0) s_tok = 0;

  // ======================= cooperative ws build =============================
  if (gtid < 8192) pace_zero(ws + W_FLG + gtid);       // flags zero (128 pairs)
  if (gtid < 50688) {
    int v = gtid / 1536, j = gtid - v * 1536;
    float a = ldv(bih, j, mode);
    for (int k = 0; k < Hn; k++)
      a += ldv(embd, (size_t)v * Hn + k, mode) * ldv(Wih, (size_t)j * Hn + k, mode);
    GEM[gtid] = a;
  }
  if (gtid < 65536) {
    int j = gtid >> 7, u = gtid & 127;
    float a = 0.f;
    for (int h = 0; h < Hn; h++)
      a += ldv(catW, (size_t)j * 1024 + 512 + h, mode) * ldv(memW, (size_t)h * UDn + u, mode);
    M2[(size_t)j * 128 + u] = a;
  }
  if (gtid < 65536) {
    int u = gtid >> 9, k = gtid & 511;
    mWT[(size_t)u * 512 + k] = ldv(memW, (size_t)k * UDn + u, mode);
  }
  if (gtid < 512) {
    int j = gtid;
    float a = ldv(catb, j, mode);
    for (int h = 0; h < Hn; h++)
      a += ldv(catW, (size_t)j * 1024 + 512 + h, mode) * ldv(memb, h, mode);
    cbF[j] = a;
  }
  __threadfence();
  __syncthreads();
  if (tid == 0) {  // poison-agnostic device barrier (one-time acq/rel is fine)
    if (blk == 0) {
      __hip_atomic_store(ws + W_INITC, 0u, __ATOMIC_RELAXED, __HIP_MEMORY_SCOPE_AGENT);
      astore(ws + W_SENT, SENT_V);
    }
    while (aload(ws + W_SENT) != SENT_V) __builtin_amdgcn_s_sleep(8);
    __hip_atomic_fetch_add(ws + W_INITC, 1u, __ATOMIC_ACQ_REL, __HIP_MEMORY_SCOPE_AGENT);
    waitGe(ws + W_INITC, NB);
  }
  __syncthreads();

  const int roff = role * 256;  // this block's j-offset

  // ======================= 500 decode steps =================================
  for (int t = 0; t < Tn; t++) {
    __syncthreads();

    // ---- GRU: 768 rows (this half), v9 ring pipeline, chains verbatim -----
    {
      const int c = lane & 7;
      f4 xv[16];
#pragma unroll
      for (int i = 0; i < 16; i++) xv[i] = *(const f4*)(h_l + c * 64 + i * 4);
      const int base = lane & 56;
      if (mode) {
        const u32 soff = (u32)((lane >> 3) * 128 + (((lane & 7) ^ (lane >> 3)) * 16));
        const char* W = (const char*)Whh;
        const int rp = lane >> 3;
#pragma unroll
        for (int r = 0; r < 8; r++) {
          const int ri = wv * 8 + r;
          const int wrow = (ri >> 8) * 512 + roff + (ri & 255);
          stage16(W + (size_t)wrow * 1024 + soff, stage + (size_t)ri * 1024);
        }
        for (int tt = 0; tt < 12; tt++) {
          if (tt < 11) {
            char* nbuf = stage + (size_t)((tt + 1) & 1) * 65536;
#pragma unroll
            for (int r = 0; r < 8; r++) {
              const int rl = wv * 8 + r, ri = (tt + 1) * 64 + rl;
              const int wrow = (ri >> 8) * 512 + roff + (ri & 255);
              stage16(W + (size_t)wrow * 1024 + soff, nbuf + (size_t)rl * 1024);
            }
            asm volatile("s_waitcnt vmcnt(8)" ::: "memory");
          } else {
            asm volatile("s_waitcnt vmcnt(0)" ::: "memory");
          }
          const char* rb = stage + (size_t)(tt & 1) * 65536 +
                           (size_t)(wv * 8 + rp) * 1024 + c * 128;
          float a = 0.f;
#pragma unroll
          for (int s = 0; s < 8; s++) {
            const u4 q = *(const u4*)(rb + ((s ^ c) * 16));
            const f4 xa = xv[s * 2], xb = xv[s * 2 + 1];
            a = fmaf(LO16(q.x), xa.x, fmaf(HI16(q.x), xa.y,
                fmaf(LO16(q.y), xa.z, fmaf(HI16(q.y), xa.w, a))));
            a = fmaf(LO16(q.z), xb.x, fmaf(HI16(q.z), xb.y,
                fmaf(LO16(q.w), xb.z, fmaf(HI16(q.w), xb.w, a))));
          }
          float sf = __shfl(a, base);
#pragma unroll
          for (int c2 = 1; c2 < 8; c2++) sf += __shfl(a, base + c2);
          if (c == 0) {
            const int ri = tt * 64 + wv * 8 + rp;
            const int wrow = (ri >> 8) * 512 + roff + (ri & 255);
            ghq[ri] = sf + bhh_l[wrow];
          }
        }
      } else {
        const u32 l4 = (u32)(lane & 15);
        const u32 cs0 = (u32)(lane >> 4), cs1 = cs0 + 4;
        const u32 soff0 = cs0 * 256 + (((l4 & 8) | ((l4 ^ cs0) & 7))) * 16;
        const u32 soff1 = cs1 * 256 + (((l4 & 8) | ((l4 ^ cs1) & 7))) * 16;
        const char* W = (const char*)Whh;
        const int rp = lane >> 3, act = (lane < 32);
#pragma unroll
        for (int r = 0; r < 4; r++) {
          const int ri = wv * 4 + r;
          const int wrow = (ri >> 8) * 512 + roff + (ri & 255);
          const char* src = W + (size_t)wrow * 2048;
          char* dst = stage + (size_t)ri * 2048;
          stage16(src + soff0, dst);
          stage16(src + soff1, dst + 1024);
        }
        for (int tt = 0; tt < 24; tt++) {
          if (tt < 23) {
            char* nbuf = stage + (size_t)((tt + 1) & 1) * 65536;
#pragma unroll
            for (int r = 0; r < 4; r++) {
              const int rl = wv * 4 + r, ri = (tt + 1) * 32 + rl;
              const int wrow = (ri >> 8) * 512 + roff + (ri & 255);
              const char* src = W + (size_t)wrow * 2048;
              char* dst = nbuf + (size_t)rl * 2048;
              stage16(src + soff0, dst);
              stage16(src + soff1, dst + 1024);
            }
            asm volatile("s_waitcnt vmcnt(8)" ::: "memory");
          } else {
            asm volatile("s_waitcnt vmcnt(0)" ::: "memory");
          }
          if (act) {
            const char* rb = stage + (size_t)(tt & 1) * 65536 +
                             (size_t)(wv * 4 + rp) * 2048 + c * 256;
            float a = 0.f;
#pragma unroll
            for (int i = 0; i < 16; i++) {
              const u32 j = (u32)((i & 8) | ((i ^ c) & 7));
              const f4 q = *(const f4*)(rb + j * 16);
              const f4 x = xv[i];
              a = fmaf(q.x, x.x, fmaf(q.y, x.y, fmaf(q.z, x.z, fmaf(q.w, x.w, a))));
            }
            float sf = __shfl(a, base);
#pragma unroll
            for (int c2 = 1; c2 < 8; c2++) sf += __shfl(a, base + c2);
            if (c == 0) {
              const int ri = tt * 32 + wv * 4 + rp;
              const int wrow = (ri >> 8) * 512 + roff + (ri & 255);
              ghq[ri] = sf + bhh_l[wrow];
            }
          }
        }
      }
    }
    // ---- B: tok(t-1) poll deferred to here (hidden under GRU dots) --------
    if (role == 1 && t > 0 && tid == 0) {
      rpoll(FLG + 4 * 8, (u32)t);
      s_tok = rloadi(&TKX[0]);
    }
    __syncthreads();

    // ---- gates (256 own rows; verbatim formulas) + publish h half ---------
    if (tid < 256) {
      const int jl = tid, jg = roff + jl;
      int tk = s_tok;
      if ((unsigned)tk > 32u) tk = 0;
      const float giR = GEM[tk * 1536 + jg];
      const float giZ = GEM[tk * 1536 + 512 + jg];
      const float giN = GEM[tk * 1536 + 1024 + jg];
      const float rr = 1.f / (1.f + expf(-(giR + ghq[jl])));
      const float zz = 1.f / (1.f + expf(-(giZ + ghq[256 + jl])));
      const float nn = tanhf(giN + rr * ghq[512 + jl]);
      const float hv = h_l[jg];
      const float hnew = (1.f - zz) * nn + zz * hv;
      h_l[jg] = hnew;
      rstoref(&HX[jg], hnew);             // relaxed atomic store (coherence pt)
    }
    __syncthreads();                      // drains vmcnt for all waves
    if (tid == 0) rarrive(FLG + role * 8);       // kind 0/1: my h half ready
    if (tid == 0) rpoll(FLG + (1 - role) * 8, (u32)(t + 1));
    __syncthreads();
    if (tid < 256) {                      // read partner's h half (relaxed)
      const int jo = (1 - role) * 256 + tid;
      h_l[jo] = rloadf(&HX[jo]);
    }
    __syncthreads();

    if (role == 0) {
      // =========== A: attention (verbatim v9) → publish cu ================
      {
        const int u = tid & 127, c8 = tid >> 7;
        const f4* mw = (const f4*)(mWT + (size_t)u * 512);
        float aa = 0.f, ab = 0.f;
#pragma unroll
        for (int b = 0; b < 2; b++) {
          f4 qa[8], qb[8];
#pragma unroll
          for (int s = 0; s < 8; s++) qa[s] = mw[c8 * 16 + b * 8 + s];
#pragma unroll
          for (int s = 0; s < 8; s++) qb[s] = mw[(c8 + 4) * 16 + b * 8 + s];
#pragma unroll
          for (int s = 0; s < 8; s++) {
            const int k0 = c8 * 64 + b * 32 + s * 4;
            const f4 xa = *(const f4*)(h_l + k0);
            aa = fmaf(qa[s].x, xa.x, aa); aa = fmaf(qa[s].y, xa.y, aa);
            aa = fmaf(qa[s].z, xa.z, aa); aa = fmaf(qa[s].w, xa.w, aa);
            const int k1 = (c8 + 4) * 64 + b * 32 + s * 4;
            const f4 xb = *(const f4*)(h_l + k1);
            ab = fmaf(qb[s].x, xb.x, ab); ab = fmaf(qb[s].y, xb.y, ab);
            ab = fmaf(qb[s].z, xb.z, ab); ab = fmaf(qb[s].w, xb.w, ab);
          }
        }
        Bpart[c8 * UDn + u] = aa;
        Bpart[(c8 + 4) * UDn + u] = ab;
      }
      __syncthreads();
      if (tid < 128) {
        float s = 0.f;
#pragma unroll
        for (int c = 0; c < 8; c++) s += Bpart[c * UDn + tid];
        ps[tid] = s;
      } else if (tid < 192) {
        const int ln = tid - 128;
        float a = 0.f;
#pragma unroll
        for (int i = 0; i < 8; i++) { int k = ln + i * 64; a = fmaf(h_l[k], ldv(memb, k, mode), a); }
        for (int o = 32; o; o >>= 1) a += __shfl_down(a, o);
        if (ln == 0) misc_l[0] = a;
      }
      __syncthreads();
#pragma unroll
      for (int rep = 0; rep < 2; rep++) {
        const int l = (wv << 5) + (lane >> 1) + rep * 256, uh = lane & 1;
        float val = 0.f;
        if (l < Ln) {
          if (mode) {
            const u4* q4 = (const u4*)((const u32*)ulat +
                                       ((size_t)pr * Ln + l) * 64 + uh * 32);
            u4 Q[8];
#pragma unroll
            for (int s = 0; s < 8; s++) Q[s] = __builtin_nontemporal_load(q4 + s);
#pragma unroll
            for (int s = 0; s < 8; s++) {
#pragma unroll
              for (int e = 0; e < 4; e++) {
                const u32 d = Q[s][e];
                const int i = s * 4 + e;
                val = fmaf(bitsf(d << 16), ps[uh * 64 + i * 2], val);
                val = fmaf(bitsf(d & 0xffff0000u), ps[uh * 64 + i * 2 + 1], val);
              }
            }
          } else {
            const float* q = (const float*)ulat + ((size_t)pr * Ln + l) * UDn + uh * 64;
#pragma unroll 8
            for (int i = 0; i < 64; i++)
              val = fmaf(__builtin_nontemporal_load(q + i), ps[uh * 64 + i], val);
          }
        }
        const float v2v = __shfl_down(val, 1);
        if ((lane & 1) == 0 && l < Ln) ss[l] = val + v2v + misc_l[0];
      }
      __syncthreads();
      if (wv == 0) {
        float mx = -3.4e38f;
        for (int i = 0; i < 8; i++) {
          int l = lane + (i << 6);
          if (l < Ln) mx = fmaxf(mx, ss[l]);
        }
        for (int o = 32; o; o >>= 1) mx = fmaxf(mx, __shfl_xor(mx, o));
        float sum = 0.f;
        for (int i = 0; i < 8; i++) {
          int l = lane + (i << 6);
          if (l < Ln) { float e = expf(ss[l] - mx); es[l] = e; sum += e; }
        }
        for (int o = 32; o; o >>= 1) sum += __shfl_xor(sum, o);
        if (lane == 0) misc_l[1] = 1.f / sum;
      }
      __syncthreads();
      {
        const int u = tid & 127, lc = tid >> 7;
        float aa = 0.f, ab = 0.f;
        if (mode) {
          const u16* q = (const u16*)ulat + ((size_t)pr * Ln) * UDn + u;
          const int e0 = (lc * 64 + 64 < Ln) ? lc * 64 + 64 : Ln;
#pragma unroll 8
          for (int l = lc * 64; l < e0; l++)
            aa = fmaf(es[l], b2f(__builtin_nontemporal_load(q + (size_t)l * UDn)), aa);
          const int e1 = ((lc + 4) * 64 + 64 < Ln) ? (lc + 4) * 64 + 64 : Ln;
#pragma unroll 8
          for (int l = (lc + 4) * 64; l < e1; l++)
            ab = fmaf(es[l], b2f(__builtin_nontemporal_load(q + (size_t)l * UDn)), ab);
        } else {
          const float* q = (const float*)ulat + ((size_t)pr * Ln) * UDn + u;
          const int e0 = (lc * 64 + 64 < Ln) ? lc * 64 + 64 : Ln;
#pragma unroll 8
          for (int l = lc * 64; l < e0; l++)
            aa = fmaf(es[l], __builtin_nontemporal_load(q + (size_t)l * UDn), aa);
          const int e1 = ((lc + 4) * 64 + 64 < Ln) ? (lc + 4) * 64 + 64 : Ln;
#pragma unroll 8
          for (int l = (lc + 4) * 64; l < e1; l++)
            ab = fmaf(es[l], __builtin_nontemporal_load(q + (size_t)l * UDn), ab);
        }
        Bpart[lc * UDn + u] = aa;
        Bpart[(lc + 4) * UDn + u] = ab;
      }
      __syncthreads();
      if (tid < 128) {
        float s = 0.f;
#pragma unroll
        for (int c = 0; c < 8; c++) s += Bpart[c * UDn + tid];
        const float cv = s * misc_l[1];
        cuv[tid] = cv;
        rstoref(&CUX[tid], cv);           // relaxed atomic store
      }
      __syncthreads();                    // vmcnt drain
      if (tid == 0) rarrive(FLG + 2 * 8); // kind2: cu ready

      // ---- A's cc rows j in [0,128): v8 register chains (verbatim) --------
      if (tid < 128) {
        const int j = tid;
        float a0 = 0.f, a1 = 0.f;
        if (mode) {
          const u4* cw = (const u4*)((const u16*)catW + (size_t)j * 1024);
          for (int b2 = 0; b2 < 4; b2++) {
            u4 q0[8], q1[8];
#pragma unroll
            for (int s2 = 0; s2 < 8; s2++) q0[s2] = cw[b2 * 8 + s2];
#pragma unroll
            for (int s2 = 0; s2 < 8; s2++) q1[s2] = cw[32 + b2 * 8 + s2];
#pragma unroll
            for (int s2 = 0; s2 < 8; s2++) {
              const int e0 = b2 * 64 + s2 * 8;
              const f4 xa = *(const f4*)(h_l + e0), xb = *(const f4*)(h_l + e0 + 4);
              a0 = fmaf(LO16(q0[s2].x), xa.x, a0); a0 = fmaf(HI16(q0[s2].x), xa.y, a0);
              a0 = fmaf(LO16(q0[s2].y), xa.z, a0); a0 = fmaf(HI16(q0[s2].y), xa.w, a0);
              a0 = fmaf(LO16(q0[s2].z), xb.x, a0); a0 = fmaf(HI16(q0[s2].z), xb.y, a0);
              a0 = fmaf(LO16(q0[s2].w), xb.z, a0); a0 = fmaf(HI16(q0[s2].w), xb.w, a0);
              const int e1 = 256 + b2 * 64 + s2 * 8;
              const f4 ya = *(const f4*)(h_l + e1), yb = *(const f4*)(h_l + e1 + 4);
              a1 = fmaf(LO16(q1[s2].x), ya.x, a1); a1 = fmaf(HI16(q1[s2].x), ya.y, a1);
              a1 = fmaf(LO16(q1[s2].y), ya.z, a1); a1 = fmaf(HI16(q1[s2].y), ya.w, a1);
              a1 = fmaf(LO16(q1[s2].z), yb.x, a1); a1 = fmaf(HI16(q1[s2].z), yb.y, a1);
              a1 = fmaf(LO16(q1[s2].w), yb.z, a1); a1 = fmaf(HI16(q1[s2].w), yb.w, a1);
            }
          }
        } else {
          const f4* cw4 = (const f4*)catW + (size_t)j * 256;
          for (int b2 = 0; b2 < 8; b2++) {
            f4 q0[8], q1[8];
#pragma unroll
            for (int s2 = 0; s2 < 8; s2++) q0[s2] = cw4[b2 * 8 + s2];
#pragma unroll
            for (int s2 = 0; s2 < 8; s2++) q1[s2] = cw4[64 + b2 * 8 + s2];
#pragma unroll
            for (int s2 = 0; s2 < 8; s2++) {
              const int e0 = b2 * 32 + s2 * 4;
              const f4 xa = *(const f4*)(h_l + e0);
              a0 = fmaf(q0[s2].x, xa.x, a0); a0 = fmaf(q0[s2].y, xa.y, a0);
              a0 = fmaf(q0[s2].z, xa.z, a0); a0 = fmaf(q0[s2].w, xa.w, a0);
              const int e1 = 256 + b2 * 32 + s2 * 4;
              const f4 ya = *(const f4*)(h_l + e1);
              a1 = fmaf(q1[s2].x, ya.x, a1); a1 = fmaf(q1[s2].y, ya.y, a1);
              a1 = fmaf(q1[s2].z, ya.z, a1); a1 = fmaf(q1[s2].w, ya.w, a1);
            }
          }
        }
        {
          const f4* m2 = (const f4*)(M2 + (size_t)j * 128);
#pragma unroll
          for (int b2 = 0; b2 < 2; b2++) {
            f4 q0[8], q1[8];
#pragma unroll
            for (int s2 = 0; s2 < 8; s2++) q0[s2] = m2[b2 * 8 + s2];
#pragma unroll
            for (int s2 = 0; s2 < 8; s2++) q1[s2] = m2[16 + b2 * 8 + s2];
#pragma unroll
            for (int s2 = 0; s2 < 8; s2++) {
              const int e0 = b2 * 32 + s2 * 4;
              const f4 xc = *(const f4*)(cuv + e0);
              a0 = fmaf(q0[s2].x, xc.x, a0); a0 = fmaf(q0[s2].y, xc.y, a0);
              a0 = fmaf(q0[s2].z, xc.z, a0); a0 = fmaf(q0[s2].w, xc.w, a0);
              const int e1 = 64 + b2 * 32 + s2 * 4;
              const f4 yc = *(const f4*)(cuv + e1);
              a1 = fmaf(q1[s2].x, yc.x, a1); a1 = fmaf(q1[s2].y, yc.y, a1);
              a1 = fmaf(q1[s2].z, yc.z, a1); a1 = fmaf(q1[s2].w, yc.w, a1);
            }
          }
        }
        ccs[j] = tanhf(a0 + a1 + cbF[j]);
      }
      if (tid == 0) rpoll(FLG + 3 * 8, (u32)(t + 1));  // ccB ready
      __syncthreads();
      if (tid >= 128) ccs[tid] = rloadf(&CCX[tid]);  // gather B's cc (relaxed)
      __syncthreads();

      // ---- logits + argmax + output (verbatim) ----------------------------
#pragma unroll
      for (int rep = 0; rep < 2; rep++) {
        if (lane < Vn) {
          const int w2i = wv + rep * 8;
          const int j0 = w2i << 5;
          float part = 0.f;
#pragma unroll
          for (int q = 0; q < 32; q++)
            part = fmaf(ccs[j0 + q], ldv(outW, (size_t)lane * Hn + j0 + q, mode), part);
          lgs[w2i * 34 + lane] = part;
        }
      }
      __syncthreads();
      if (wv == 0) {
        float lg = -3.4e38f;
        int idx = 0;
        if (lane < Vn) {
          float s = ldv(outb, lane, mode);
#pragma unroll
          for (int w2 = 0; w2 < 16; w2++) s += lgs[w2 * 34 + lane];
          if (mode) ((u16*)out)[(size_t)pr * (Vn * Ln) + lane * Ln + t] = f2b(s);
          else ((float*)out)[(size_t)pr * (Vn * Ln) + lane * Ln + t] = s;
          lg = s;
          idx = lane;
        }
        for (int o = 32; o; o >>= 1) {
          const float ov = __shfl_down(lg, o);
          const int oi = __shfl_down(idx, o);
          if (ov > lg || (ov == lg && oi < idx)) { lg = ov; idx = oi; }
        }
        if (lane == 0) { s_tok = idx; rstorei(&TKX[0], idx); }
        asm volatile("s_waitcnt vmcnt(0)" ::: "memory");
        if (lane == 0) rarrive(FLG + 4 * 8);  // kind4: token ready
      }
    } else {
      // =========== B: cc catW-part (h-only) overlapped, then finish =======
      if (mode) {
        const char* CW = (const char*)catW;
#pragma unroll
        for (int r = 0; r < 8; r++) {
          const int rl = wv * 8 + r, row = 128 + rl;
          const u32 so = (u32)(((lane ^ row) & 63) << 4);
          stage16(CW + (size_t)row * 2048 + so, stage + (size_t)rl * 1024);
        }
        for (int tt = 0; tt < 6; tt++) {
          if (tt < 5) {
            char* nbuf = stage + (size_t)((tt + 1) & 1) * 65536;
#pragma unroll
            for (int r = 0; r < 8; r++) {
              const int rl = wv * 8 + r, row = 128 + (tt + 1) * 64 + rl;
              const u32 so = (u32)(((lane ^ row) & 63) << 4);
              stage16(CW + (size_t)row * 2048 + so, nbuf + (size_t)rl * 1024);
            }
            asm volatile("s_waitcnt vmcnt(8)" ::: "memory");
          } else {
            asm volatile("s_waitcnt vmcnt(0)" ::: "memory");
          }
          __builtin_amdgcn_sched_barrier(0);
          __builtin_amdgcn_s_barrier();
          if (wv == tt) {
            const char* rb = stage + (size_t)(tt & 1) * 65536 + (size_t)lane * 1024;
            float a0 = 0.f, a1 = 0.f;
            for (int b2 = 0; b2 < 4; b2++) {
              u4 q0[8], q1[8];
#pragma unroll
              for (int s2 = 0; s2 < 8; s2++)
                q0[s2] = *(const u4*)(rb + ((((b2 * 8 + s2) ^ lane) & 63) << 4));
#pragma unroll
              for (int s2 = 0; s2 < 8; s2++)
                q1[s2] = *(const u4*)(rb + ((((32 + b2 * 8 + s2) ^ lane) & 63) << 4));
#pragma unroll
              for (int s2 = 0; s2 < 8; s2++) {
                const int e0 = b2 * 64 + s2 * 8;
                const f4 xa = *(const f4*)(h_l + e0), xb = *(const f4*)(h_l + e0 + 4);
                a0 = fmaf(LO16(q0[s2].x), xa.x, a0); a0 = fmaf(HI16(q0[s2].x), xa.y, a0);
                a0 = fmaf(LO16(q0[s2].y), xa.z, a0); a0 = fmaf(HI16(q0[s2].y), xa.w, a0);
                a0 = fmaf(LO16(q0[s2].z), xb.x, a0); a0 = fmaf(HI16(q0[s2].z), xb.y, a0);
                a0 = fmaf(LO16(q0[s2].w), xb.z, a0); a0 = fmaf(HI16(q0[s2].w), xb.w, a0);
                const int e1 = 256 + b2 * 64 + s2 * 8;
                const f4 ya = *(const f4*)(h_l + e1), yb = *(const f4*)(h_l + e1 + 4);
                a1 = fmaf(LO16(q1[s2].x), ya.x, a1); a1 = fmaf(HI16(q1[s2].x), ya.y, a1);
                a1 = fmaf(LO16(q1[s2].y), ya.z, a1); a1 = fmaf(HI16(q1[s2].y), ya.w, a1);
                a1 = fmaf(LO16(q1[s2].z), yb.x, a1); a1 = fmaf(HI16(q1[s2].z), yb.y, a1);
                a1 = fmaf(LO16(q1[s2].w), yb.z, a1); a1 = fmaf(HI16(q1[s2].w), yb.w, a1);
              }
            }
            const int bi = tt * 64 + lane;
            pa[bi * 2] = a0; pa[bi * 2 + 1] = a1;
          }
          __builtin_amdgcn_s_barrier();
        }
        __syncthreads();
      } else {
        if (tid < 384) {
          const int j = 128 + tid;
          float a0 = 0.f, a1 = 0.f;
          const f4* cw4 = (const f4*)catW + (size_t)j * 256;
          for (int b2 = 0; b2 < 8; b2++) {
            f4 q0[8], q1[8];
#pragma unroll
            for (int s2 = 0; s2 < 8; s2++) q0[s2] = cw4[b2 * 8 + s2];
#pragma unroll
            for (int s2 = 0; s2 < 8; s2++) q1[s2] = cw4[64 + b2 * 8 + s2];
#pragma unroll
            for (int s2 = 0; s2 < 8; s2++) {
              const int e0 = b2 * 32 + s2 * 4;
              const f4 xa = *(const f4*)(h_l + e0);
              a0 = fmaf(q0[s2].x, xa.x, a0); a0 = fmaf(q0[s2].y, xa.y, a0);
              a0 = fmaf(q0[s2].z, xa.z, a0); a0 = fmaf(q0[s2].w, xa.w, a0);
              const int e1 = 256 + b2 * 32 + s2 * 4;
              const f4 ya = *(const f4*)(h_l + e1);
              a1 = fmaf(q1[s2].x, ya.x, a1); a1 = fmaf(q1[s2].y, ya.y, a1);
              a1 = fmaf(q1[s2].z, ya.z, a1); a1 = fmaf(q1[s2].w, ya.w, a1);
            }
          }
          pa[tid * 2] = a0; pa[tid * 2 + 1] = a1;
        }
        __syncthreads();
      }
      // wait for cu, read it (relaxed), finish rows with verbatim M2 chains
      if (tid == 0) rpoll(FLG + 2 * 8, (u32)(t + 1));
      __syncthreads();
      if (tid < 128) cuv[tid] = rloadf(&CUX[tid]);
      __syncthreads();
      if (tid < 384) {
        const int j = 128 + tid;
        float a0 = pa[tid * 2], a1 = pa[tid * 2 + 1];
        const f4* m2 = (const f4*)(M2 + (size_t)j * 128);
#pragma unroll
        for (int b2 = 0; b2 < 2; b2++) {
          f4 q0[8], q1[8];
#pragma unroll
          for (int s2 = 0; s2 < 8; s2++) q0[s2] = m2[b2 * 8 + s2];
#pragma unroll
          for (int s2 = 0; s2 < 8; s2++) q1[s2] = m2[16 + b2 * 8 + s2];
#pragma unroll
          for (int s2 = 0; s2 < 8; s2++) {
            const int e0 = b2 * 32 + s2 * 4;
            const f4 xc = *(const f4*)(cuv + e0);
            a0 = fmaf(q0[s2].x, xc.x, a0); a0 = fmaf(q0[s2].y, xc.y, a0);
            a0 = fmaf(q0[s2].z, xc.z, a0); a0 = fmaf(q0[s2].w, xc.w, a0);
            const int e1 = 64 + b2 * 32 + s2 * 4;
            const f4 yc = *(const f4*)(cuv + e1);
            a1 = fmaf(q1[s2].x, yc.x, a1); a1 = fmaf(q1[s2].y, yc.y, a1);
            a1 = fmaf(q1[s2].z, yc.z, a1); a1 = fmaf(q1[s2].w, yc.w, a1);
          }
        }
        rstoref(&CCX[j], tanhf(a0 + a1 + cbF[j]));  // relaxed atomic store
      }
      __syncthreads();                      // vmcnt drain
      if (tid == 0) rarrive(FLG + 3 * 8);   // kind3: ccB ready
      // (tok poll moved to next step's GRU tail — hidden under GRU dots)
    }
  }
}

extern "C" void kernel_launch(void* const* d_in, const int* in_sizes, int n_in,
                              void* d_out, int out_size, void* d_ws, size_t ws_size,
                              hipStream_t stream) {
  (void)in_sizes; (void)n_in; (void)out_size;
  if (ws_size < (size_t)W_END * 4) return;  // needs ~1.36 MB scratch
  hipLaunchKernelGGL(rnn_v13, dim3(NB), dim3(NT), 0, stream,
                     d_in[0],   // latent
                     d_in[1],   // upsampled_latent
                     d_in[3],   // embed (d_in[2]=target unused in eval)
                     d_in[4],   // hid_W
                     d_in[5],   // hid_b
                     d_in[6],   // mem_W
                     d_in[7],   // mem_b
                     d_in[8],   // W_ih
                     d_in[9],   // W_hh
                     d_in[10],  // b_ih
                     d_in[11],  // b_hh
                     d_in[12],  // cat_W
                     d_in[13],  // cat_b
                     d_in[14],  // out_W
                     d_in[15],  // out_b
                     d_out, (u32*)d_ws);
}